// Round 1
// baseline (2309.552 us; speedup 1.0000x reference)
//
#include <hip/hip_runtime.h>

typedef __attribute__((ext_vector_type(8))) short short8;
typedef __attribute__((ext_vector_type(4))) float f32x4;

// ---------- helpers ----------
__device__ __forceinline__ unsigned short f2bf(float f) {
  unsigned int u = __float_as_uint(f);
  u = u + 0x7fffu + ((u >> 16) & 1u);   // RNE
  return (unsigned short)(u >> 16);
}
__device__ __forceinline__ float bf2f(unsigned short h) {
  return __uint_as_float(((unsigned int)h) << 16);
}
// element (r,k) of a [R][128] bf16 tile -> swizzled byte offset
__device__ __forceinline__ int swz(int r, int k) {
  return (((r * 128 + k) * 2) ^ ((r & 7) << 4));
}

// ---------- CSR build ----------
__global__ void k_deg(const int* __restrict__ edst, int* __restrict__ degi, int E) {
  int e = blockIdx.x * 256 + threadIdx.x;
  if (e < E) atomicAdd(&degi[edst[e]], 1);
}

__global__ void k_node(const int* __restrict__ degi, int* __restrict__ start,
                       float* __restrict__ dis, int* __restrict__ total, int N) {
  int tid = threadIdx.x;
  int i = blockIdx.x * 256 + tid;
  int d = (i < N) ? degi[i] : 0;
  __shared__ int sd[256];
  sd[tid] = d; __syncthreads();
  #pragma unroll
  for (int off = 1; off < 256; off <<= 1) {
    int v = (tid >= off) ? sd[tid - off] : 0;
    __syncthreads();
    sd[tid] += v;
    __syncthreads();
  }
  __shared__ int sbase;
  if (tid == 255) sbase = atomicAdd(total, sd[255]);
  __syncthreads();
  if (i < N) {
    start[i] = sbase + sd[tid] - d;   // exclusive prefix within global alloc
    dis[i] = rsqrtf(1.0f + (float)d);
  }
}

__global__ void k_fill(const int* __restrict__ esrc, const int* __restrict__ edst,
                       const int* __restrict__ start, int* __restrict__ cursor,
                       const float* __restrict__ dis, int* __restrict__ col,
                       float* __restrict__ wgt, int E) {
  int e = blockIdx.x * 256 + threadIdx.x;
  if (e >= E) return;
  int d = edst[e], s = esrc[e];
  int p = start[d] + atomicAdd(&cursor[d], 1);
  col[p] = s;
  wgt[p] = dis[s] * dis[d];
}

// ---------- weight transpose (Wt[m][c][k] = W[k][c], fp32) ----------
__global__ void k_wt(const float* __restrict__ Wp, const float* __restrict__ Wr,
                     const float* __restrict__ Wo0, const float* __restrict__ Wo1,
                     float* __restrict__ Wt) {
  int idx = blockIdx.x * 256 + threadIdx.x;
  if (idx >= 8 * 16384) return;
  int m = idx >> 14, rem = idx & 16383;
  int c = rem >> 7, k = rem & 127;
  float v;
  if (m == 0)       v = Wp[k * 128 + c];
  else if (m <= 4)  v = Wr[(m - 1) * 16384 + k * 128 + c];
  else if (m == 5)  v = Wo0[k * 128 + c];
  else if (m == 6)  v = Wo0[(128 + k) * 128 + c];
  else              v = Wo1[k * 128 + c];
  Wt[m * 16384 + c * 128 + k] = v;
}

// ---------- GEMM: T[N,128] (+)= A[N,128] @ W ; bf16x3 split for fp32 accuracy ----------
// LDS 64KB: As_hi, As_lo, Ws_hi, Ws_lo each [64][128] bf16 = 16KB
#define AHI_OFF 0
#define ALO_OFF 16384
#define WHI_OFF 32768
#define WLO_OFF 49152

template<bool ACC, bool RELU_A>
__global__ __launch_bounds__(256)
void k_gemm(const float* __restrict__ A, const float* __restrict__ Wt,
            float* __restrict__ T, int N) {
  __shared__ __align__(16) char smem[65536];
  const int tid = threadIdx.x;
  const int grow = blockIdx.x * 64;
  const int cb = blockIdx.y * 64;

  // staging: 64x128 of A and 64x128 of Wt (this block's col half)
  #pragma unroll
  for (int it = 0; it < 4; ++it) {
    int id = it * 256 + tid;
    int r = id >> 4;            // 0..63
    int kp = (id & 15) * 8;     // 0..120
    // A tile
    int ga = grow + r; if (ga > N - 1) ga = N - 1;
    const float* ap = A + (size_t)ga * 128 + kp;
    float4 a0 = *(const float4*)ap;
    float4 a1 = *(const float4*)(ap + 4);
    if (RELU_A) {
      a0.x = fmaxf(a0.x, 0.f); a0.y = fmaxf(a0.y, 0.f); a0.z = fmaxf(a0.z, 0.f); a0.w = fmaxf(a0.w, 0.f);
      a1.x = fmaxf(a1.x, 0.f); a1.y = fmaxf(a1.y, 0.f); a1.z = fmaxf(a1.z, 0.f); a1.w = fmaxf(a1.w, 0.f);
    }
    {
      float fv[8] = {a0.x, a0.y, a0.z, a0.w, a1.x, a1.y, a1.z, a1.w};
      short8 hi, lo;
      #pragma unroll
      for (int q = 0; q < 8; ++q) {
        unsigned short h = f2bf(fv[q]);
        hi[q] = (short)h;
        lo[q] = (short)f2bf(fv[q] - bf2f(h));
      }
      *(short8*)(smem + AHI_OFF + swz(r, kp)) = hi;
      *(short8*)(smem + ALO_OFF + swz(r, kp)) = lo;
    }
    // W tile (Wt layout [c][k])
    const float* wp = Wt + (size_t)(cb + r) * 128 + kp;
    float4 w0 = *(const float4*)wp;
    float4 w1 = *(const float4*)(wp + 4);
    {
      float fv[8] = {w0.x, w0.y, w0.z, w0.w, w1.x, w1.y, w1.z, w1.w};
      short8 hi, lo;
      #pragma unroll
      for (int q = 0; q < 8; ++q) {
        unsigned short h = f2bf(fv[q]);
        hi[q] = (short)h;
        lo[q] = (short)f2bf(fv[q] - bf2f(h));
      }
      *(short8*)(smem + WHI_OFF + swz(r, kp)) = hi;
      *(short8*)(smem + WLO_OFF + swz(r, kp)) = lo;
    }
  }
  __syncthreads();

  const int l = tid & 63;
  const int w = tid >> 6;           // 0..3
  const int wr = (w >> 1) * 32;     // 0 or 32
  const int wc = (w & 1) * 32;      // 0 or 32
  const int lr = l & 15;
  const int lk = (l >> 4) * 8;

  f32x4 acc[2][2];
  #pragma unroll
  for (int i = 0; i < 2; ++i)
    #pragma unroll
    for (int j = 0; j < 2; ++j)
      acc[i][j] = (f32x4){0.f, 0.f, 0.f, 0.f};

  #pragma unroll
  for (int kk = 0; kk < 4; ++kk) {
    int k0 = kk * 32 + lk;
    short8 ahi[2], alo[2], bhi[2], blo[2];
    #pragma unroll
    for (int i = 0; i < 2; ++i) {
      int r = wr + i * 16 + lr;
      ahi[i] = *(const short8*)(smem + AHI_OFF + swz(r, k0));
      alo[i] = *(const short8*)(smem + ALO_OFF + swz(r, k0));
    }
    #pragma unroll
    for (int j = 0; j < 2; ++j) {
      int c = wc + j * 16 + lr;
      bhi[j] = *(const short8*)(smem + WHI_OFF + swz(c, k0));
      blo[j] = *(const short8*)(smem + WLO_OFF + swz(c, k0));
    }
    #pragma unroll
    for (int i = 0; i < 2; ++i)
      #pragma unroll
      for (int j = 0; j < 2; ++j) {
        acc[i][j] = __builtin_amdgcn_mfma_f32_16x16x32_bf16(ahi[i], bhi[j], acc[i][j], 0, 0, 0);
        acc[i][j] = __builtin_amdgcn_mfma_f32_16x16x32_bf16(ahi[i], blo[j], acc[i][j], 0, 0, 0);
        acc[i][j] = __builtin_amdgcn_mfma_f32_16x16x32_bf16(alo[i], bhi[j], acc[i][j], 0, 0, 0);
      }
  }

  // epilogue: D row=(l>>4)*4+r, col=l&15 (HW-verified layout)
  #pragma unroll
  for (int i = 0; i < 2; ++i)
    #pragma unroll
    for (int j = 0; j < 2; ++j)
      #pragma unroll
      for (int r = 0; r < 4; ++r) {
        int row = grow + wr + i * 16 + (l >> 4) * 4 + r;
        int c = cb + wc + j * 16 + lr;
        if (row < N) {
          size_t idx = (size_t)row * 128 + c;
          if (ACC) T[idx] += acc[i][j][r];
          else     T[idx]  = acc[i][j][r];
        }
      }
}

// ---------- aggregation: h[i] = relu( sum_in t[src]*w + t[i]*dis^2 + b ) ----------
__global__ __launch_bounds__(256)
void k_agg(const float* __restrict__ t, const int* __restrict__ col, const float* __restrict__ wgt,
           const int* __restrict__ start, const int* __restrict__ degi, const float* __restrict__ dis,
           const float* __restrict__ bias, float* __restrict__ hout, int N) {
  int node = blockIdx.x * 4 + (threadIdx.x >> 6);
  if (node >= N) return;
  int lane = threadIdx.x & 63;
  float dsv = dis[node];
  float sn = dsv * dsv;
  float2 tv = *(const float2*)(t + (size_t)node * 128 + lane * 2);
  float2 bv = *(const float2*)(bias + lane * 2);
  float ax = tv.x * sn + bv.x;
  float ay = tv.y * sn + bv.y;
  int s = start[node], d = degi[node];
  for (int base = 0; base < d; base += 64) {
    int m = min(64, d - base);
    int ce = 0; float we = 0.f;
    if (lane < m) { ce = col[s + base + lane]; we = wgt[s + base + lane]; }
    float2 r0, r1;
    r0.x = r0.y = r1.x = r1.y = 0.f;
    if (m >= 1) { int s0 = __shfl(ce, 0); r0 = *(const float2*)(t + (size_t)s0 * 128 + lane * 2); }
    if (m >= 2) { int s1 = __shfl(ce, 1); r1 = *(const float2*)(t + (size_t)s1 * 128 + lane * 2); }
    int j = 0;
    for (; j + 2 < m; j += 2) {
      float wa = __shfl(we, j);
      float wb = __shfl(we, j + 1);
      int sa = __shfl(ce, j + 2);
      float2 n0 = *(const float2*)(t + (size_t)sa * 128 + lane * 2);
      float2 n1; n1.x = 0.f; n1.y = 0.f;
      bool h3 = (j + 3 < m);
      if (h3) { int sb = __shfl(ce, j + 3); n1 = *(const float2*)(t + (size_t)sb * 128 + lane * 2); }
      ax += r0.x * wa; ay += r0.y * wa;
      ax += r1.x * wb; ay += r1.y * wb;
      r0 = n0; r1 = h3 ? n1 : n0;
    }
    if (j < m)     { float wa = __shfl(we, j);     ax += r0.x * wa; ay += r0.y * wa; }
    if (j + 1 < m) { float wb = __shfl(we, j + 1); ax += r1.x * wb; ay += r1.y * wb; }
  }
  float2 o; o.x = fmaxf(ax, 0.f); o.y = fmaxf(ay, 0.f);
  *(float2*)(hout + (size_t)node * 128 + lane * 2) = o;
}

// ---------- pooling ----------
__global__ void k_gb(const int* __restrict__ batch, int* __restrict__ gstart, int N) {
  int i = blockIdx.x * 256 + threadIdx.x;
  if (i < N) atomicMin(&gstart[batch[i]], i);
}

__global__ void k_pool(const float* __restrict__ h, const int* __restrict__ gstart,
                       float* __restrict__ out, int N) {
  int g = blockIdx.x;
  int tid = threadIdx.x;
  __shared__ int s_lo, s_cnt;
  if (tid == 0) {
    int end = N;
    for (int gg = g + 1; gg < 64; ++gg) end = min(end, gstart[gg]);
    int lo = gstart[g];
    if (lo > end) lo = end;
    s_lo = lo; s_cnt = end - lo;
  }
  __syncthreads();
  int lo = s_lo, cnt = s_cnt;
  float acc = 0.f;
  for (int i = 0; i < cnt; ++i) acc += h[(size_t)(lo + i) * 128 + tid];
  out[g * 128 + tid] = acc / (float)(cnt > 0 ? cnt : 1);
}

// ---------- launcher ----------
extern "C" void kernel_launch(void* const* d_in, const int* in_sizes, int n_in,
                              void* d_out, int out_size, void* d_ws, size_t ws_size,
                              hipStream_t stream) {
  const float* x   = (const float*)d_in[0];
  const float* Wp  = (const float*)d_in[1];
  const float* bp  = (const float*)d_in[2];
  const float* Wr  = (const float*)d_in[3];
  const float* br  = (const float*)d_in[4];
  const float* Wo0 = (const float*)d_in[5];
  const float* bo0 = (const float*)d_in[6];
  const float* Wo1 = (const float*)d_in[7];
  const float* bo1 = (const float*)d_in[8];
  const int* esrc  = (const int*)d_in[9];
  const int* edst  = (const int*)d_in[10];
  const int* batch = (const int*)d_in[11];
  const int E = in_sizes[9];
  const int N = in_sizes[11];
  float* out = (float*)d_out;

  char* wsp = (char*)d_ws;
  size_t off = 0;
  auto alloc = [&](size_t bytes) {
    void* p = wsp + off;
    off += (bytes + 255) & ~(size_t)255;
    return p;
  };
  float* t      = (float*)alloc((size_t)N * 128 * 4);
  float* h      = (float*)alloc((size_t)N * 128 * 4);
  int*   col    = (int*)alloc((size_t)E * 4);
  float* wgt    = (float*)alloc((size_t)E * 4);
  int*   start  = (int*)alloc((size_t)N * 4);
  int*   degi   = (int*)alloc((size_t)N * 4);
  int*   cursor = (int*)alloc((size_t)N * 4);
  float* dis    = (float*)alloc((size_t)N * 4);
  float* Wt     = (float*)alloc((size_t)8 * 16384 * 4);
  int*   gstart = (int*)alloc(64 * 4);
  int*   total  = (int*)alloc(16);

  hipMemsetAsync(degi,   0,    (size_t)N * 4, stream);
  hipMemsetAsync(cursor, 0,    (size_t)N * 4, stream);
  hipMemsetAsync(total,  0,    4, stream);
  hipMemsetAsync(gstart, 0x7F, 64 * 4, stream);

  k_deg <<<(E + 255) / 256, 256, 0, stream>>>(edst, degi, E);
  k_node<<<(N + 255) / 256, 256, 0, stream>>>(degi, start, dis, total, N);
  k_fill<<<(E + 255) / 256, 256, 0, stream>>>(esrc, edst, start, cursor, dis, col, wgt, E);
  k_wt  <<<512, 256, 0, stream>>>(Wp, Wr, Wo0, Wo1, Wt);
  k_gb  <<<(N + 255) / 256, 256, 0, stream>>>(batch, gstart, N);

  dim3 ggrid((N + 63) / 64, 2);

  // L0: t = x @ Wp ; h = agg(t, bp)
  k_gemm<false, false><<<ggrid, 256, 0, stream>>>(x, Wt + 0 * 16384, t, N);
  k_agg<<<(N + 3) / 4, 256, 0, stream>>>(t, col, wgt, start, degi, dis, bp, h, N);
  // L1..L4 recurrent
  for (int i = 0; i < 4; ++i) {
    k_gemm<false, false><<<ggrid, 256, 0, stream>>>(h, Wt + (1 + i) * 16384, t, N);
    k_agg<<<(N + 3) / 4, 256, 0, stream>>>(t, col, wgt, start, degi, dis, br + i * 128, h, N);
  }
  // L5: t = h @ Wo0_top + relu(x) @ Wo0_bot ; h = agg(t, bo0)
  k_gemm<false, false><<<ggrid, 256, 0, stream>>>(h, Wt + 5 * 16384, t, N);
  k_gemm<true,  true ><<<ggrid, 256, 0, stream>>>(x, Wt + 6 * 16384, t, N);
  k_agg<<<(N + 3) / 4, 256, 0, stream>>>(t, col, wgt, start, degi, dis, bo0, h, N);
  // L6: t = h @ Wo1 ; h = agg(t, bo1)
  k_gemm<false, false><<<ggrid, 256, 0, stream>>>(h, Wt + 7 * 16384, t, N);
  k_agg<<<(N + 3) / 4, 256, 0, stream>>>(t, col, wgt, start, degi, dis, bo1, h, N);

  // mean pool
  k_pool<<<64, 128, 0, stream>>>(h, gstart, out, N);
}

// Round 7
// 1431.663 us; speedup vs baseline: 1.6132x; 1.6132x over previous
//
#include <hip/hip_runtime.h>

typedef __attribute__((ext_vector_type(8))) short short8;
typedef __attribute__((ext_vector_type(4))) float f32x4;

// ---------- helpers ----------
__device__ __forceinline__ unsigned short f2bf(float f) {
  unsigned int u = __float_as_uint(f);
  u = u + 0x7fffu + ((u >> 16) & 1u);   // RNE
  return (unsigned short)(u >> 16);
}
__device__ __forceinline__ float bf2f(unsigned short h) {
  return __uint_as_float(((unsigned int)h) << 16);
}
// element (r,k) of a [R][128] bf16 tile -> swizzled byte offset
__device__ __forceinline__ int swz(int r, int k) {
  return (((r * 128 + k) * 2) ^ ((r & 7) << 4));
}

// ---------- CSR build ----------
__global__ void k_deg(const int* __restrict__ edst, int* __restrict__ degi, int E) {
  int e = blockIdx.x * 256 + threadIdx.x;
  if (e < E) atomicAdd(&degi[edst[e]], 1);
}

__global__ void k_node(const int* __restrict__ degi, int* __restrict__ start,
                       float* __restrict__ dis, int* __restrict__ total, int N) {
  int tid = threadIdx.x;
  int i = blockIdx.x * 256 + tid;
  int d = (i < N) ? degi[i] : 0;
  __shared__ int sd[256];
  sd[tid] = d; __syncthreads();
  #pragma unroll
  for (int off = 1; off < 256; off <<= 1) {
    int v = (tid >= off) ? sd[tid - off] : 0;
    __syncthreads();
    sd[tid] += v;
    __syncthreads();
  }
  __shared__ int sbase;
  if (tid == 255) sbase = atomicAdd(total, sd[255]);
  __syncthreads();
  if (i < N) {
    start[i] = sbase + sd[tid] - d;   // exclusive prefix within global alloc
    dis[i] = rsqrtf(1.0f + (float)d);
  }
}

__global__ void k_fill(const int* __restrict__ esrc, const int* __restrict__ edst,
                       const int* __restrict__ start, int* __restrict__ cursor,
                       const float* __restrict__ dis, int* __restrict__ col,
                       float* __restrict__ wgt, int E) {
  int e = blockIdx.x * 256 + threadIdx.x;
  if (e >= E) return;
  int d = edst[e], s = esrc[e];
  int p = start[d] + atomicAdd(&cursor[d], 1);
  col[p] = s;
  wgt[p] = dis[s] * dis[d];
}

// ---------- weight transpose (Wt[m][c][k] = W[k][c], fp32) ----------
__global__ void k_wt(const float* __restrict__ Wp, const float* __restrict__ Wr,
                     const float* __restrict__ Wo0, const float* __restrict__ Wo1,
                     float* __restrict__ Wt) {
  int idx = blockIdx.x * 256 + threadIdx.x;
  if (idx >= 8 * 16384) return;
  int m = idx >> 14, rem = idx & 16383;
  int c = rem >> 7, k = rem & 127;
  float v;
  if (m == 0)       v = Wp[k * 128 + c];
  else if (m <= 4)  v = Wr[(m - 1) * 16384 + k * 128 + c];
  else if (m == 5)  v = Wo0[k * 128 + c];
  else if (m == 6)  v = Wo0[(128 + k) * 128 + c];
  else              v = Wo1[k * 128 + c];
  Wt[m * 16384 + c * 128 + k] = v;
}

// ---------- GEMM: T[N,128] (+)= A[N,128] @ W ; bf16x3 split for fp32 accuracy ----------
#define AHI_OFF 0
#define ALO_OFF 16384
#define WHI_OFF 32768
#define WLO_OFF 49152

template<bool ACC, bool RELU_A>
__global__ __launch_bounds__(256)
void k_gemm(const float* __restrict__ A, const float* __restrict__ Wt,
            float* __restrict__ T, int N) {
  __shared__ __align__(16) char smem[65536];
  const int tid = threadIdx.x;
  const int grow = blockIdx.x * 64;
  const int cb = blockIdx.y * 64;

  #pragma unroll
  for (int it = 0; it < 4; ++it) {
    int id = it * 256 + tid;
    int r = id >> 4;            // 0..63
    int kp = (id & 15) * 8;     // 0..120
    int ga = grow + r; if (ga > N - 1) ga = N - 1;
    const float* ap = A + (size_t)ga * 128 + kp;
    float4 a0 = *(const float4*)ap;
    float4 a1 = *(const float4*)(ap + 4);
    if (RELU_A) {
      a0.x = fmaxf(a0.x, 0.f); a0.y = fmaxf(a0.y, 0.f); a0.z = fmaxf(a0.z, 0.f); a0.w = fmaxf(a0.w, 0.f);
      a1.x = fmaxf(a1.x, 0.f); a1.y = fmaxf(a1.y, 0.f); a1.z = fmaxf(a1.z, 0.f); a1.w = fmaxf(a1.w, 0.f);
    }
    {
      float fv[8] = {a0.x, a0.y, a0.z, a0.w, a1.x, a1.y, a1.z, a1.w};
      short8 hi, lo;
      #pragma unroll
      for (int q = 0; q < 8; ++q) {
        unsigned short hh = f2bf(fv[q]);
        hi[q] = (short)hh;
        lo[q] = (short)f2bf(fv[q] - bf2f(hh));
      }
      *(short8*)(smem + AHI_OFF + swz(r, kp)) = hi;
      *(short8*)(smem + ALO_OFF + swz(r, kp)) = lo;
    }
    const float* wp = Wt + (size_t)(cb + r) * 128 + kp;
    float4 w0 = *(const float4*)wp;
    float4 w1 = *(const float4*)(wp + 4);
    {
      float fv[8] = {w0.x, w0.y, w0.z, w0.w, w1.x, w1.y, w1.z, w1.w};
      short8 hi, lo;
      #pragma unroll
      for (int q = 0; q < 8; ++q) {
        unsigned short hh = f2bf(fv[q]);
        hi[q] = (short)hh;
        lo[q] = (short)f2bf(fv[q] - bf2f(hh));
      }
      *(short8*)(smem + WHI_OFF + swz(r, kp)) = hi;
      *(short8*)(smem + WLO_OFF + swz(r, kp)) = lo;
    }
  }
  __syncthreads();

  const int l = tid & 63;
  const int w = tid >> 6;           // 0..3
  const int wr = (w >> 1) * 32;     // 0 or 32
  const int wc = (w & 1) * 32;      // 0 or 32
  const int lr = l & 15;
  const int lk = (l >> 4) * 8;

  f32x4 acc[2][2];
  #pragma unroll
  for (int i = 0; i < 2; ++i)
    #pragma unroll
    for (int j = 0; j < 2; ++j)
      acc[i][j] = (f32x4){0.f, 0.f, 0.f, 0.f};

  #pragma unroll
  for (int kk = 0; kk < 4; ++kk) {
    int k0 = kk * 32 + lk;
    short8 ahi[2], alo[2], bhi[2], blo[2];
    #pragma unroll
    for (int i = 0; i < 2; ++i) {
      int r = wr + i * 16 + lr;
      ahi[i] = *(const short8*)(smem + AHI_OFF + swz(r, k0));
      alo[i] = *(const short8*)(smem + ALO_OFF + swz(r, k0));
    }
    #pragma unroll
    for (int j = 0; j < 2; ++j) {
      int c = wc + j * 16 + lr;
      bhi[j] = *(const short8*)(smem + WHI_OFF + swz(c, k0));
      blo[j] = *(const short8*)(smem + WLO_OFF + swz(c, k0));
    }
    #pragma unroll
    for (int i = 0; i < 2; ++i)
      #pragma unroll
      for (int j = 0; j < 2; ++j) {
        acc[i][j] = __builtin_amdgcn_mfma_f32_16x16x32_bf16(ahi[i], bhi[j], acc[i][j], 0, 0, 0);
        acc[i][j] = __builtin_amdgcn_mfma_f32_16x16x32_bf16(ahi[i], blo[j], acc[i][j], 0, 0, 0);
        acc[i][j] = __builtin_amdgcn_mfma_f32_16x16x32_bf16(alo[i], bhi[j], acc[i][j], 0, 0, 0);
      }
  }

  #pragma unroll
  for (int i = 0; i < 2; ++i)
    #pragma unroll
    for (int j = 0; j < 2; ++j)
      #pragma unroll
      for (int r = 0; r < 4; ++r) {
        int row = grow + wr + i * 16 + (l >> 4) * 4 + r;
        int c = cb + wc + j * 16 + lr;
        if (row < N) {
          size_t idx = (size_t)row * 128 + c;
          if (ACC) T[idx] += acc[i][j][r];
          else     T[idx]  = acc[i][j][r];
        }
      }
}

// ---------- aggregation: h[i] = relu( sum_in t[src]*w + t[i]*dis^2 + b ) ----------
// R0-proven version (measured PASS at 4.88e-4): one wave per node, float2/lane,
// sequential edges, uniform (non-divergent) pipeline.
__global__ __launch_bounds__(256)
void k_agg(const float* __restrict__ t, const int* __restrict__ col, const float* __restrict__ wgt,
           const int* __restrict__ start, const int* __restrict__ degi, const float* __restrict__ dis,
           const float* __restrict__ bias, float* __restrict__ hout, int N) {
  int node = blockIdx.x * 4 + (threadIdx.x >> 6);
  if (node >= N) return;
  int lane = threadIdx.x & 63;
  float dsv = dis[node];
  float sn = dsv * dsv;
  float2 tv = *(const float2*)(t + (size_t)node * 128 + lane * 2);
  float2 bv = *(const float2*)(bias + lane * 2);
  float ax = tv.x * sn + bv.x;
  float ay = tv.y * sn + bv.y;
  int s = start[node], d = degi[node];
  for (int base = 0; base < d; base += 64) {
    int m = min(64, d - base);
    int ce = 0; float we = 0.f;
    if (lane < m) { ce = col[s + base + lane]; we = wgt[s + base + lane]; }
    float2 r0, r1;
    r0.x = r0.y = r1.x = r1.y = 0.f;
    if (m >= 1) { int s0 = __shfl(ce, 0); r0 = *(const float2*)(t + (size_t)s0 * 128 + lane * 2); }
    if (m >= 2) { int s1 = __shfl(ce, 1); r1 = *(const float2*)(t + (size_t)s1 * 128 + lane * 2); }
    int j = 0;
    for (; j + 2 < m; j += 2) {
      float wa = __shfl(we, j);
      float wb = __shfl(we, j + 1);
      int sa = __shfl(ce, j + 2);
      float2 n0 = *(const float2*)(t + (size_t)sa * 128 + lane * 2);
      float2 n1; n1.x = 0.f; n1.y = 0.f;
      bool h3 = (j + 3 < m);
      if (h3) { int sb = __shfl(ce, j + 3); n1 = *(const float2*)(t + (size_t)sb * 128 + lane * 2); }
      ax += r0.x * wa; ay += r0.y * wa;
      ax += r1.x * wb; ay += r1.y * wb;
      r0 = n0; r1 = h3 ? n1 : n0;
    }
    if (j < m)     { float wa = __shfl(we, j);     ax += r0.x * wa; ay += r0.y * wa; }
    if (j + 1 < m) { float wb = __shfl(we, j + 1); ax += r1.x * wb; ay += r1.y * wb; }
  }
  float2 o; o.x = fmaxf(ax, 0.f); o.y = fmaxf(ay, 0.f);
  *(float2*)(hout + (size_t)node * 128 + lane * 2) = o;
}

// ---------- pooling ----------
// batch is SORTED -> boundary detection, no atomics. gstart has 65 entries.
__global__ void k_gb(const int* __restrict__ batch, int* __restrict__ gstart, int N) {
  int i = blockIdx.x * 256 + threadIdx.x;
  if (i >= N) return;
  int b = batch[i];
  int prev = (i == 0) ? -1 : batch[i - 1];
  if (b != prev) {
    for (int g = prev + 1; g <= b; ++g) gstart[g] = i;  // fills empty-graph gaps
  }
  if (i == N - 1) {
    for (int g = b + 1; g <= 64; ++g) gstart[g] = N;
  }
}

// stage 1: 4 chunks per graph, 512 threads (4 row-waves x 128 feats), no atomics
__global__ __launch_bounds__(512)
void k_pool1(const float* __restrict__ h, const int* __restrict__ gstart,
             float* __restrict__ part) {
  int g = blockIdx.x >> 2, c = blockIdx.x & 3;
  int lo = gstart[g], hi = gstart[g + 1];
  int cnt = hi - lo;
  int c0 = lo + (int)(((long long)cnt * c) >> 2);
  int c1 = lo + (int)(((long long)cnt * (c + 1)) >> 2);
  int r = threadIdx.x >> 7;      // 0..3
  int f = threadIdx.x & 127;
  float acc = 0.f;
  for (int i = c0 + r; i < c1; i += 4) acc += h[(size_t)i * 128 + f];
  __shared__ float s[4][128];
  s[r][f] = acc;
  __syncthreads();
  if (r == 0)
    part[(size_t)blockIdx.x * 128 + f] = s[0][f] + s[1][f] + s[2][f] + s[3][f];
}

// stage 2: combine 4 partials, divide by count
__global__ void k_pool2(const float* __restrict__ part, const int* __restrict__ gstart,
                        float* __restrict__ out) {
  int g = blockIdx.x, f = threadIdx.x;
  int cnt = gstart[g + 1] - gstart[g];
  float s = part[(size_t)(g * 4 + 0) * 128 + f] + part[(size_t)(g * 4 + 1) * 128 + f]
          + part[(size_t)(g * 4 + 2) * 128 + f] + part[(size_t)(g * 4 + 3) * 128 + f];
  out[g * 128 + f] = s / (float)(cnt > 0 ? cnt : 1);
}

// ---------- launcher ----------
extern "C" void kernel_launch(void* const* d_in, const int* in_sizes, int n_in,
                              void* d_out, int out_size, void* d_ws, size_t ws_size,
                              hipStream_t stream) {
  const float* x   = (const float*)d_in[0];
  const float* Wp  = (const float*)d_in[1];
  const float* bp  = (const float*)d_in[2];
  const float* Wr  = (const float*)d_in[3];
  const float* br  = (const float*)d_in[4];
  const float* Wo0 = (const float*)d_in[5];
  const float* bo0 = (const float*)d_in[6];
  const float* Wo1 = (const float*)d_in[7];
  const float* bo1 = (const float*)d_in[8];
  const int* esrc  = (const int*)d_in[9];
  const int* edst  = (const int*)d_in[10];
  const int* batch = (const int*)d_in[11];
  const int E = in_sizes[9];
  const int N = in_sizes[11];
  float* out = (float*)d_out;

  char* wsp = (char*)d_ws;
  size_t off = 0;
  auto alloc = [&](size_t bytes) {
    void* p = wsp + off;
    off += (bytes + 255) & ~(size_t)255;
    return p;
  };
  float* t      = (float*)alloc((size_t)N * 128 * 4);
  float* h      = (float*)alloc((size_t)N * 128 * 4);
  int*   col    = (int*)alloc((size_t)E * 4);
  float* wgt    = (float*)alloc((size_t)E * 4);
  int*   start  = (int*)alloc((size_t)N * 4);
  int*   degi   = (int*)alloc((size_t)N * 4);
  int*   cursor = (int*)alloc((size_t)N * 4);   // reused as `part` after CSR build
  float* dis    = (float*)alloc((size_t)N * 4);
  float* Wt     = (float*)alloc((size_t)8 * 16384 * 4);
  int*   gstart = (int*)alloc(65 * 4);
  int*   total  = (int*)alloc(16);
  float* part   = (float*)cursor;               // 256*128*4 = 128KB <= N*4 = 400KB

  hipMemsetAsync(degi,   0, (size_t)N * 4, stream);
  hipMemsetAsync(cursor, 0, (size_t)N * 4, stream);
  hipMemsetAsync(total,  0, 4, stream);

  k_deg <<<(E + 255) / 256, 256, 0, stream>>>(edst, degi, E);
  k_node<<<(N + 255) / 256, 256, 0, stream>>>(degi, start, dis, total, N);
  k_fill<<<(E + 255) / 256, 256, 0, stream>>>(esrc, edst, start, cursor, dis, col, wgt, E);
  k_wt  <<<512, 256, 0, stream>>>(Wp, Wr, Wo0, Wo1, Wt);
  k_gb  <<<(N + 255) / 256, 256, 0, stream>>>(batch, gstart, N);

  dim3 ggrid((N + 63) / 64, 2);

  // L0: t = x @ Wp ; h = agg(t, bp)
  k_gemm<false, false><<<ggrid, 256, 0, stream>>>(x, Wt + 0 * 16384, t, N);
  k_agg<<<(N + 3) / 4, 256, 0, stream>>>(t, col, wgt, start, degi, dis, bp, h, N);
  // L1..L4 recurrent
  for (int i = 0; i < 4; ++i) {
    k_gemm<false, false><<<ggrid, 256, 0, stream>>>(h, Wt + (1 + i) * 16384, t, N);
    k_agg<<<(N + 3) / 4, 256, 0, stream>>>(t, col, wgt, start, degi, dis, br + i * 128, h, N);
  }
  // L5: t = h @ Wo0_top + relu(x) @ Wo0_bot ; h = agg(t, bo0)
  k_gemm<false, false><<<ggrid, 256, 0, stream>>>(h, Wt + 5 * 16384, t, N);
  k_gemm<true,  true ><<<ggrid, 256, 0, stream>>>(x, Wt + 6 * 16384, t, N);
  k_agg<<<(N + 3) / 4, 256, 0, stream>>>(t, col, wgt, start, degi, dis, bo0, h, N);
  // L6: t = h @ Wo1 ; h = agg(t, bo1)
  k_gemm<false, false><<<ggrid, 256, 0, stream>>>(h, Wt + 7 * 16384, t, N);
  k_agg<<<(N + 3) / 4, 256, 0, stream>>>(t, col, wgt, start, degi, dis, bo1, h, N);

  // mean pool (2-stage, deterministic)
  k_pool1<<<256, 512, 0, stream>>>(h, gstart, part);
  k_pool2<<<64, 128, 0, stream>>>(part, gstart, out);
}

// Round 9
// 1381.493 us; speedup vs baseline: 1.6718x; 1.0363x over previous
//
#include <hip/hip_runtime.h>

typedef __attribute__((ext_vector_type(8))) short short8;
typedef __attribute__((ext_vector_type(4))) float f32x4;

// ---------- helpers ----------
__device__ __forceinline__ unsigned short f2bf(float f) {
  unsigned int u = __float_as_uint(f);
  u = u + 0x7fffu + ((u >> 16) & 1u);   // RNE
  return (unsigned short)(u >> 16);
}
__device__ __forceinline__ float bf2f(unsigned short h) {
  return __uint_as_float(((unsigned int)h) << 16);
}
// element (r,k) of a [R][128] bf16 tile -> swizzled byte offset
__device__ __forceinline__ int swz(int r, int k) {
  return (((r * 128 + k) * 2) ^ ((r & 7) << 4));
}

// ---------- CSR build ----------
__global__ void k_deg(const int* __restrict__ edst, int* __restrict__ degi, int E) {
  int e = blockIdx.x * 256 + threadIdx.x;
  if (e < E) atomicAdd(&degi[edst[e]], 1);
}

__global__ void k_node(const int* __restrict__ degi, int* __restrict__ start,
                       float* __restrict__ dis, int* __restrict__ total, int N) {
  int tid = threadIdx.x;
  int i = blockIdx.x * 256 + tid;
  int d = (i < N) ? degi[i] : 0;
  __shared__ int sd[256];
  sd[tid] = d; __syncthreads();
  #pragma unroll
  for (int off = 1; off < 256; off <<= 1) {
    int v = (tid >= off) ? sd[tid - off] : 0;
    __syncthreads();
    sd[tid] += v;
    __syncthreads();
  }
  __shared__ int sbase;
  if (tid == 255) sbase = atomicAdd(total, sd[255]);
  __syncthreads();
  if (i < N) {
    start[i] = sbase + sd[tid] - d;   // exclusive prefix within global alloc
    dis[i] = rsqrtf(1.0f + (float)d);
  }
}

__global__ void k_fill(const int* __restrict__ esrc, const int* __restrict__ edst,
                       const int* __restrict__ start, int* __restrict__ cursor,
                       const float* __restrict__ dis, int* __restrict__ col,
                       float* __restrict__ wgt, int E) {
  int e = blockIdx.x * 256 + threadIdx.x;
  if (e >= E) return;
  int d = edst[e], s = esrc[e];
  int p = start[d] + atomicAdd(&cursor[d], 1);
  col[p] = s;
  wgt[p] = dis[s] * dis[d];
}

// ---------- weight prep: bf16 hi/lo split of W^T, computed ONCE ----------
// Whi/Wlo layout [m][c][k] (k contiguous), m = layer slot 0..7
__global__ void k_wt(const float* __restrict__ Wp, const float* __restrict__ Wr,
                     const float* __restrict__ Wo0, const float* __restrict__ Wo1,
                     unsigned short* __restrict__ Whi, unsigned short* __restrict__ Wlo) {
  int idx = blockIdx.x * 256 + threadIdx.x;
  if (idx >= 8 * 16384) return;
  int m = idx >> 14, rem = idx & 16383;
  int c = rem >> 7, k = rem & 127;
  float v;
  if (m == 0)       v = Wp[k * 128 + c];
  else if (m <= 4)  v = Wr[(m - 1) * 16384 + k * 128 + c];
  else if (m == 5)  v = Wo0[k * 128 + c];
  else if (m == 6)  v = Wo0[(128 + k) * 128 + c];
  else              v = Wo1[k * 128 + c];
  unsigned short hh = f2bf(v);
  Whi[idx] = hh;
  Wlo[idx] = f2bf(v - bf2f(hh));
}

// ---------- GEMM: T[N,128] (+)= A[N,128] @ W ; bf16x3 split for fp32 accuracy ----------
#define AHI_OFF 0
#define ALO_OFF 16384
#define WHI_OFF 32768
#define WLO_OFF 49152

template<bool ACC, bool RELU_A>
__global__ __launch_bounds__(256)
void k_gemm(const float* __restrict__ A, const unsigned short* __restrict__ Whi,
            const unsigned short* __restrict__ Wlo, float* __restrict__ T, int N) {
  __shared__ __align__(16) char smem[65536];
  const int tid = threadIdx.x;
  const int grow = blockIdx.x * 64;
  const int cb = blockIdx.y * 64;

  #pragma unroll
  for (int it = 0; it < 4; ++it) {
    int id = it * 256 + tid;
    int r = id >> 4;            // 0..63
    int kp = (id & 15) * 8;     // 0..120
    int ga = grow + r; if (ga > N - 1) ga = N - 1;
    const float* ap = A + (size_t)ga * 128 + kp;
    float4 a0 = *(const float4*)ap;
    float4 a1 = *(const float4*)(ap + 4);
    if (RELU_A) {
      a0.x = fmaxf(a0.x, 0.f); a0.y = fmaxf(a0.y, 0.f); a0.z = fmaxf(a0.z, 0.f); a0.w = fmaxf(a0.w, 0.f);
      a1.x = fmaxf(a1.x, 0.f); a1.y = fmaxf(a1.y, 0.f); a1.z = fmaxf(a1.z, 0.f); a1.w = fmaxf(a1.w, 0.f);
    }
    {
      float fv[8] = {a0.x, a0.y, a0.z, a0.w, a1.x, a1.y, a1.z, a1.w};
      short8 hi, lo;
      #pragma unroll
      for (int q = 0; q < 8; ++q) {
        unsigned short hh = f2bf(fv[q]);
        hi[q] = (short)hh;
        lo[q] = (short)f2bf(fv[q] - bf2f(hh));
      }
      *(short8*)(smem + AHI_OFF + swz(r, kp)) = hi;
      *(short8*)(smem + ALO_OFF + swz(r, kp)) = lo;
    }
    // W tile: pre-split bf16, straight copy global -> LDS
    size_t wo = (size_t)(cb + r) * 128 + kp;
    *(short8*)(smem + WHI_OFF + swz(r, kp)) = *(const short8*)(Whi + wo);
    *(short8*)(smem + WLO_OFF + swz(r, kp)) = *(const short8*)(Wlo + wo);
  }
  __syncthreads();

  const int l = tid & 63;
  const int w = tid >> 6;           // 0..3
  const int wr = (w >> 1) * 32;     // 0 or 32
  const int wc = (w & 1) * 32;      // 0 or 32
  const int lr = l & 15;
  const int lk = (l >> 4) * 8;

  f32x4 acc[2][2];
  #pragma unroll
  for (int i = 0; i < 2; ++i)
    #pragma unroll
    for (int j = 0; j < 2; ++j)
      acc[i][j] = (f32x4){0.f, 0.f, 0.f, 0.f};

  #pragma unroll
  for (int kk = 0; kk < 4; ++kk) {
    int k0 = kk * 32 + lk;
    short8 ahi[2], alo[2], bhi[2], blo[2];
    #pragma unroll
    for (int i = 0; i < 2; ++i) {
      int r = wr + i * 16 + lr;
      ahi[i] = *(const short8*)(smem + AHI_OFF + swz(r, k0));
      alo[i] = *(const short8*)(smem + ALO_OFF + swz(r, k0));
    }
    #pragma unroll
    for (int j = 0; j < 2; ++j) {
      int c = wc + j * 16 + lr;
      bhi[j] = *(const short8*)(smem + WHI_OFF + swz(c, k0));
      blo[j] = *(const short8*)(smem + WLO_OFF + swz(c, k0));
    }
    #pragma unroll
    for (int i = 0; i < 2; ++i)
      #pragma unroll
      for (int j = 0; j < 2; ++j) {
        acc[i][j] = __builtin_amdgcn_mfma_f32_16x16x32_bf16(ahi[i], bhi[j], acc[i][j], 0, 0, 0);
        acc[i][j] = __builtin_amdgcn_mfma_f32_16x16x32_bf16(ahi[i], blo[j], acc[i][j], 0, 0, 0);
        acc[i][j] = __builtin_amdgcn_mfma_f32_16x16x32_bf16(alo[i], bhi[j], acc[i][j], 0, 0, 0);
      }
  }

  #pragma unroll
  for (int i = 0; i < 2; ++i)
    #pragma unroll
    for (int j = 0; j < 2; ++j)
      #pragma unroll
      for (int r = 0; r < 4; ++r) {
        int row = grow + wr + i * 16 + (l >> 4) * 4 + r;
        int c = cb + wc + j * 16 + lr;
        if (row < N) {
          size_t idx = (size_t)row * 128 + c;
          if (ACC) T[idx] += acc[i][j][r];
          else     T[idx]  = acc[i][j][r];
        }
      }
}

// ---------- aggregation: h[i] = relu( sum_in t[src]*w + t[i]*dis^2 + b ) ----------
// One wave per node. Pair-gather: two 32-lane halves each fetch a different
// edge row as f32x4/lane (512B coalesced per row), 4 pairs in flight.
// UNIFORM control flow: npairs is wave-uniform; phantom slots (idx >= m) use
// shfl index (ii&63) into fully-initialized lanes and weight 0.
__global__ __launch_bounds__(256)
void k_agg(const float* __restrict__ t, const int* __restrict__ col, const float* __restrict__ wgt,
           const int* __restrict__ start, const int* __restrict__ degi, const float* __restrict__ dis,
           const float* __restrict__ bias, float* __restrict__ hout, int N) {
  int node = blockIdx.x * 4 + (threadIdx.x >> 6);
  if (node >= N) return;
  int lane = threadIdx.x & 63;
  int half = lane >> 5;          // 0 or 1
  int fo = (lane & 31) * 4;      // feature offset (f32x4 per lane)

  float dsv = dis[node];
  float sn = dsv * dsv;
  f32x4 acc = (f32x4){0.f, 0.f, 0.f, 0.f};
  if (half == 0) {
    f32x4 tv = *(const f32x4*)(t + (size_t)node * 128 + fo);
    f32x4 bv = *(const f32x4*)(bias + fo);
    acc = tv * sn + bv;
  }

#define LOADP(k, rr, ww) { int ii = 2 * (k) + half;                       \
    int ss = __shfl(ce, ii & 63); float wv = __shfl(we, ii & 63);         \
    ww = (ii < m) ? wv : 0.f;                                             \
    rr = *(const f32x4*)(t + (size_t)ss * 128 + fo); }

  int s = start[node], d = degi[node];
  for (int base = 0; base < d; base += 64) {
    int m = min(64, d - base);           // wave-uniform
    int ce = 0; float we = 0.f;
    if (lane < m) { ce = col[s + base + lane]; we = wgt[s + base + lane]; }
    int npairs = (m + 1) >> 1;           // wave-uniform
    f32x4 p0, p1, p2, p3; float w0, w1, w2, w3;
    LOADP(0, p0, w0); LOADP(1, p1, w1); LOADP(2, p2, w2); LOADP(3, p3, w3);
    int q = 0;
    for (; q + 4 < npairs; q += 4) {
      acc += p0 * w0; LOADP(q + 4, p0, w0);
      acc += p1 * w1; LOADP(q + 5, p1, w1);
      acc += p2 * w2; LOADP(q + 6, p2, w2);
      acc += p3 * w3; LOADP(q + 7, p3, w3);
    }
    acc += p0 * w0; acc += p1 * w1; acc += p2 * w2; acc += p3 * w3;
  }
#undef LOADP

  // combine halves (lane pairs with lane^32 hold the same features)
  acc[0] += __shfl_xor(acc[0], 32);
  acc[1] += __shfl_xor(acc[1], 32);
  acc[2] += __shfl_xor(acc[2], 32);
  acc[3] += __shfl_xor(acc[3], 32);

  if (half == 0) {
    f32x4 o;
    o[0] = fmaxf(acc[0], 0.f); o[1] = fmaxf(acc[1], 0.f);
    o[2] = fmaxf(acc[2], 0.f); o[3] = fmaxf(acc[3], 0.f);
    *(f32x4*)(hout + (size_t)node * 128 + fo) = o;
  }
}

// ---------- pooling ----------
// batch is SORTED -> boundary detection, no atomics. gstart has 65 entries.
__global__ void k_gb(const int* __restrict__ batch, int* __restrict__ gstart, int N) {
  int i = blockIdx.x * 256 + threadIdx.x;
  if (i >= N) return;
  int b = batch[i];
  int prev = (i == 0) ? -1 : batch[i - 1];
  if (b != prev) {
    for (int g = prev + 1; g <= b; ++g) gstart[g] = i;  // fills empty-graph gaps
  }
  if (i == N - 1) {
    for (int g = b + 1; g <= 64; ++g) gstart[g] = N;
  }
}

// stage 1: 4 chunks per graph, 512 threads (4 row-waves x 128 feats), no atomics
__global__ __launch_bounds__(512)
void k_pool1(const float* __restrict__ h, const int* __restrict__ gstart,
             float* __restrict__ part) {
  int g = blockIdx.x >> 2, c = blockIdx.x & 3;
  int lo = gstart[g], hi = gstart[g + 1];
  int cnt = hi - lo;
  int c0 = lo + (int)(((long long)cnt * c) >> 2);
  int c1 = lo + (int)(((long long)cnt * (c + 1)) >> 2);
  int r = threadIdx.x >> 7;      // 0..3
  int f = threadIdx.x & 127;
  float acc = 0.f;
  for (int i = c0 + r; i < c1; i += 4) acc += h[(size_t)i * 128 + f];
  __shared__ float s[4][128];
  s[r][f] = acc;
  __syncthreads();
  if (r == 0)
    part[(size_t)blockIdx.x * 128 + f] = s[0][f] + s[1][f] + s[2][f] + s[3][f];
}

// stage 2: combine 4 partials, divide by count
__global__ void k_pool2(const float* __restrict__ part, const int* __restrict__ gstart,
                        float* __restrict__ out) {
  int g = blockIdx.x, f = threadIdx.x;
  int cnt = gstart[g + 1] - gstart[g];
  float s = part[(size_t)(g * 4 + 0) * 128 + f] + part[(size_t)(g * 4 + 1) * 128 + f]
          + part[(size_t)(g * 4 + 2) * 128 + f] + part[(size_t)(g * 4 + 3) * 128 + f];
  out[g * 128 + f] = s / (float)(cnt > 0 ? cnt : 1);
}

// ---------- launcher ----------
extern "C" void kernel_launch(void* const* d_in, const int* in_sizes, int n_in,
                              void* d_out, int out_size, void* d_ws, size_t ws_size,
                              hipStream_t stream) {
  const float* x   = (const float*)d_in[0];
  const float* Wp  = (const float*)d_in[1];
  const float* bp  = (const float*)d_in[2];
  const float* Wr  = (const float*)d_in[3];
  const float* br  = (const float*)d_in[4];
  const float* Wo0 = (const float*)d_in[5];
  const float* bo0 = (const float*)d_in[6];
  const float* Wo1 = (const float*)d_in[7];
  const float* bo1 = (const float*)d_in[8];
  const int* esrc  = (const int*)d_in[9];
  const int* edst  = (const int*)d_in[10];
  const int* batch = (const int*)d_in[11];
  const int E = in_sizes[9];
  const int N = in_sizes[11];
  float* out = (float*)d_out;

  char* wsp = (char*)d_ws;
  size_t off = 0;
  auto alloc = [&](size_t bytes) {
    void* p = wsp + off;
    off += (bytes + 255) & ~(size_t)255;
    return p;
  };
  float* t      = (float*)alloc((size_t)N * 128 * 4);
  float* h      = (float*)alloc((size_t)N * 128 * 4);
  int*   col    = (int*)alloc((size_t)E * 4);
  float* wgt    = (float*)alloc((size_t)E * 4);
  int*   start  = (int*)alloc((size_t)N * 4);
  int*   degi   = (int*)alloc((size_t)N * 4);
  int*   cursor = (int*)alloc((size_t)N * 4);   // reused as `part` after CSR build
  float* dis    = (float*)alloc((size_t)N * 4);
  unsigned short* Whi = (unsigned short*)alloc((size_t)8 * 16384 * 2);  // same 512KB
  unsigned short* Wlo = (unsigned short*)alloc((size_t)8 * 16384 * 2);  // as old fp32 Wt
  int*   gstart = (int*)alloc(65 * 4);
  int*   total  = (int*)alloc(16);
  float* part   = (float*)cursor;               // 256*128*4 = 128KB <= N*4 = 400KB

  hipMemsetAsync(degi,   0, (size_t)N * 4, stream);
  hipMemsetAsync(cursor, 0, (size_t)N * 4, stream);
  hipMemsetAsync(total,  0, 4, stream);

  k_deg <<<(E + 255) / 256, 256, 0, stream>>>(edst, degi, E);
  k_node<<<(N + 255) / 256, 256, 0, stream>>>(degi, start, dis, total, N);
  k_fill<<<(E + 255) / 256, 256, 0, stream>>>(esrc, edst, start, cursor, dis, col, wgt, E);
  k_wt  <<<512, 256, 0, stream>>>(Wp, Wr, Wo0, Wo1, Whi, Wlo);
  k_gb  <<<(N + 255) / 256, 256, 0, stream>>>(batch, gstart, N);

  dim3 ggrid((N + 63) / 64, 2);

  // L0: t = x @ Wp ; h = agg(t, bp)
  k_gemm<false, false><<<ggrid, 256, 0, stream>>>(x, Whi + 0 * 16384, Wlo + 0 * 16384, t, N);
  k_agg<<<(N + 3) / 4, 256, 0, stream>>>(t, col, wgt, start, degi, dis, bp, h, N);
  // L1..L4 recurrent
  for (int i = 0; i < 4; ++i) {
    k_gemm<false, false><<<ggrid, 256, 0, stream>>>(h, Whi + (1 + i) * 16384, Wlo + (1 + i) * 16384, t, N);
    k_agg<<<(N + 3) / 4, 256, 0, stream>>>(t, col, wgt, start, degi, dis, br + i * 128, h, N);
  }
  // L5: t = h @ Wo0_top + relu(x) @ Wo0_bot ; h = agg(t, bo0)
  k_gemm<false, false><<<ggrid, 256, 0, stream>>>(h, Whi + 5 * 16384, Wlo + 5 * 16384, t, N);
  k_gemm<true,  true ><<<ggrid, 256, 0, stream>>>(x, Whi + 6 * 16384, Wlo + 6 * 16384, t, N);
  k_agg<<<(N + 3) / 4, 256, 0, stream>>>(t, col, wgt, start, degi, dis, bo0, h, N);
  // L6: t = h @ Wo1 ; h = agg(t, bo1)
  k_gemm<false, false><<<ggrid, 256, 0, stream>>>(h, Whi + 7 * 16384, Wlo + 7 * 16384, t, N);
  k_agg<<<(N + 3) / 4, 256, 0, stream>>>(t, col, wgt, start, degi, dis, bo1, h, N);

  // mean pool (2-stage, deterministic)
  k_pool1<<<256, 512, 0, stream>>>(h, gstart, part);
  k_pool2<<<64, 128, 0, stream>>>(part, gstart, out);
}

// Round 11
// 995.614 us; speedup vs baseline: 2.3197x; 1.3876x over previous
//
#include <hip/hip_runtime.h>

typedef __attribute__((ext_vector_type(8))) short short8;
typedef __attribute__((ext_vector_type(4))) float f32x4;
typedef __attribute__((ext_vector_type(4))) unsigned short us4;

// ---------- helpers ----------
__device__ __forceinline__ unsigned short f2bf(float f) {
  unsigned int u = __float_as_uint(f);
  u = u + 0x7fffu + ((u >> 16) & 1u);   // RNE
  return (unsigned short)(u >> 16);
}
__device__ __forceinline__ float bf2f(unsigned short h) {
  return __uint_as_float(((unsigned int)h) << 16);
}
// element (r,k) of a [R][128] bf16 tile -> swizzled byte offset
__device__ __forceinline__ int swz(int r, int k) {
  return (((r * 128 + k) * 2) ^ ((r & 7) << 4));
}

// ---------- CSR build ----------
__global__ void k_deg(const int* __restrict__ edst, int* __restrict__ degi, int E) {
  int e = blockIdx.x * 256 + threadIdx.x;
  if (e < E) atomicAdd(&degi[edst[e]], 1);
}

__global__ void k_node(const int* __restrict__ degi, int* __restrict__ start,
                       float* __restrict__ dis, int* __restrict__ total, int N) {
  int tid = threadIdx.x;
  int i = blockIdx.x * 256 + tid;
  int d = (i < N) ? degi[i] : 0;
  __shared__ int sd[256];
  sd[tid] = d; __syncthreads();
  #pragma unroll
  for (int off = 1; off < 256; off <<= 1) {
    int v = (tid >= off) ? sd[tid - off] : 0;
    __syncthreads();
    sd[tid] += v;
    __syncthreads();
  }
  __shared__ int sbase;
  if (tid == 255) sbase = atomicAdd(total, sd[255]);
  __syncthreads();
  if (i < N) {
    start[i] = sbase + sd[tid] - d;   // exclusive prefix within global alloc
    dis[i] = rsqrtf(1.0f + (float)d);
  }
}

__global__ void k_fill(const int* __restrict__ esrc, const int* __restrict__ edst,
                       const int* __restrict__ start, int* __restrict__ cursor,
                       const float* __restrict__ dis, int* __restrict__ col,
                       float* __restrict__ wgt, int E) {
  int e = blockIdx.x * 256 + threadIdx.x;
  if (e >= E) return;
  int d = edst[e], s = esrc[e];
  int p = start[d] + atomicAdd(&cursor[d], 1);
  col[p] = s;
  wgt[p] = dis[s] * dis[d];
}

// ---------- weight prep: bf16 hi/lo split of W^T, computed ONCE ----------
// Whi/Wlo layout [m][c][k] (k contiguous), m = layer slot 0..7
__global__ void k_wt(const float* __restrict__ Wp, const float* __restrict__ Wr,
                     const float* __restrict__ Wo0, const float* __restrict__ Wo1,
                     unsigned short* __restrict__ Whi, unsigned short* __restrict__ Wlo) {
  int idx = blockIdx.x * 256 + threadIdx.x;
  if (idx >= 8 * 16384) return;
  int m = idx >> 14, rem = idx & 16383;
  int c = rem >> 7, k = rem & 127;
  float v;
  if (m == 0)       v = Wp[k * 128 + c];
  else if (m <= 4)  v = Wr[(m - 1) * 16384 + k * 128 + c];
  else if (m == 5)  v = Wo0[k * 128 + c];
  else if (m == 6)  v = Wo0[(128 + k) * 128 + c];
  else              v = Wo1[k * 128 + c];
  unsigned short hh = f2bf(v);
  Whi[idx] = hh;
  Wlo[idx] = f2bf(v - bf2f(hh));
}

// ---------- GEMM: TB[N,128](bf16) (+)= A[N,128](f32) @ W ; bf16x3 split ----------
#define AHI_OFF 0
#define ALO_OFF 16384
#define WHI_OFF 32768
#define WLO_OFF 49152

template<bool ACC, bool RELU_A>
__global__ __launch_bounds__(256)
void k_gemm(const float* __restrict__ A, const unsigned short* __restrict__ Whi,
            const unsigned short* __restrict__ Wlo, unsigned short* __restrict__ TB, int N) {
  __shared__ __align__(16) char smem[65536];
  const int tid = threadIdx.x;
  const int grow = blockIdx.x * 64;
  const int cb = blockIdx.y * 64;

  #pragma unroll
  for (int it = 0; it < 4; ++it) {
    int id = it * 256 + tid;
    int r = id >> 4;            // 0..63
    int kp = (id & 15) * 8;     // 0..120
    int ga = grow + r; if (ga > N - 1) ga = N - 1;
    const float* ap = A + (size_t)ga * 128 + kp;
    float4 a0 = *(const float4*)ap;
    float4 a1 = *(const float4*)(ap + 4);
    if (RELU_A) {
      a0.x = fmaxf(a0.x, 0.f); a0.y = fmaxf(a0.y, 0.f); a0.z = fmaxf(a0.z, 0.f); a0.w = fmaxf(a0.w, 0.f);
      a1.x = fmaxf(a1.x, 0.f); a1.y = fmaxf(a1.y, 0.f); a1.z = fmaxf(a1.z, 0.f); a1.w = fmaxf(a1.w, 0.f);
    }
    {
      float fv[8] = {a0.x, a0.y, a0.z, a0.w, a1.x, a1.y, a1.z, a1.w};
      short8 hi, lo;
      #pragma unroll
      for (int q = 0; q < 8; ++q) {
        unsigned short hh = f2bf(fv[q]);
        hi[q] = (short)hh;
        lo[q] = (short)f2bf(fv[q] - bf2f(hh));
      }
      *(short8*)(smem + AHI_OFF + swz(r, kp)) = hi;
      *(short8*)(smem + ALO_OFF + swz(r, kp)) = lo;
    }
    // W tile: pre-split bf16, straight copy global -> LDS
    size_t wo = (size_t)(cb + r) * 128 + kp;
    *(short8*)(smem + WHI_OFF + swz(r, kp)) = *(const short8*)(Whi + wo);
    *(short8*)(smem + WLO_OFF + swz(r, kp)) = *(const short8*)(Wlo + wo);
  }
  __syncthreads();

  const int l = tid & 63;
  const int w = tid >> 6;           // 0..3
  const int wr = (w >> 1) * 32;     // 0 or 32
  const int wc = (w & 1) * 32;      // 0 or 32
  const int lr = l & 15;
  const int lk = (l >> 4) * 8;

  f32x4 acc[2][2];
  #pragma unroll
  for (int i = 0; i < 2; ++i)
    #pragma unroll
    for (int j = 0; j < 2; ++j)
      acc[i][j] = (f32x4){0.f, 0.f, 0.f, 0.f};

  #pragma unroll
  for (int kk = 0; kk < 4; ++kk) {
    int k0 = kk * 32 + lk;
    short8 ahi[2], alo[2], bhi[2], blo[2];
    #pragma unroll
    for (int i = 0; i < 2; ++i) {
      int r = wr + i * 16 + lr;
      ahi[i] = *(const short8*)(smem + AHI_OFF + swz(r, k0));
      alo[i] = *(const short8*)(smem + ALO_OFF + swz(r, k0));
    }
    #pragma unroll
    for (int j = 0; j < 2; ++j) {
      int c = wc + j * 16 + lr;
      bhi[j] = *(const short8*)(smem + WHI_OFF + swz(c, k0));
      blo[j] = *(const short8*)(smem + WLO_OFF + swz(c, k0));
    }
    #pragma unroll
    for (int i = 0; i < 2; ++i)
      #pragma unroll
      for (int j = 0; j < 2; ++j) {
        acc[i][j] = __builtin_amdgcn_mfma_f32_16x16x32_bf16(ahi[i], bhi[j], acc[i][j], 0, 0, 0);
        acc[i][j] = __builtin_amdgcn_mfma_f32_16x16x32_bf16(ahi[i], blo[j], acc[i][j], 0, 0, 0);
        acc[i][j] = __builtin_amdgcn_mfma_f32_16x16x32_bf16(alo[i], bhi[j], acc[i][j], 0, 0, 0);
      }
  }

  #pragma unroll
  for (int i = 0; i < 2; ++i)
    #pragma unroll
    for (int j = 0; j < 2; ++j)
      #pragma unroll
      for (int r = 0; r < 4; ++r) {
        int row = grow + wr + i * 16 + (l >> 4) * 4 + r;
        int c = cb + wc + j * 16 + lr;
        if (row < N) {
          size_t idx = (size_t)row * 128 + c;
          float v = acc[i][j][r];
          if (ACC) v += bf2f(TB[idx]);
          TB[idx] = f2bf(v);
        }
      }
}

// ---------- aggregation: h[i] = relu( sum_in tb[src]*w + tb[i]*dis^2 + b ) ----------
// One wave per node. Pair-gather over bf16 rows (256B each): two 32-lane
// halves fetch different edge rows as us4 (8B)/lane, 4 pairs in flight.
// UNIFORM control flow (proven R9): phantom slots weight 0, shfl idx &63.
__global__ __launch_bounds__(256)
void k_agg(const unsigned short* __restrict__ tb, const int* __restrict__ col,
           const float* __restrict__ wgt, const int* __restrict__ start,
           const int* __restrict__ degi, const float* __restrict__ dis,
           const float* __restrict__ bias, float* __restrict__ hout, int N) {
  int node = blockIdx.x * 4 + (threadIdx.x >> 6);
  if (node >= N) return;
  int lane = threadIdx.x & 63;
  int half = lane >> 5;          // 0 or 1
  int fq = (lane & 31) * 4;      // feature offset (4 features per lane)

  float dsv = dis[node];
  float sn = dsv * dsv;
  f32x4 acc = (f32x4){0.f, 0.f, 0.f, 0.f};
  if (half == 0) {
    us4 sv = *(const us4*)(tb + (size_t)node * 128 + fq);
    float4 bv = *(const float4*)(bias + fq);
    acc[0] = bf2f(sv[0]) * sn + bv.x;
    acc[1] = bf2f(sv[1]) * sn + bv.y;
    acc[2] = bf2f(sv[2]) * sn + bv.z;
    acc[3] = bf2f(sv[3]) * sn + bv.w;
  }

#define LOADP(k, rr, ww) { int ii = 2 * (k) + half;                       \
    int ss = __shfl(ce, ii & 63); float wv = __shfl(we, ii & 63);         \
    ww = (ii < m) ? wv : 0.f;                                             \
    us4 u = *(const us4*)(tb + (size_t)ss * 128 + fq);                    \
    rr[0] = bf2f(u[0]); rr[1] = bf2f(u[1]);                               \
    rr[2] = bf2f(u[2]); rr[3] = bf2f(u[3]); }

  int s = start[node], d = degi[node];
  for (int base = 0; base < d; base += 64) {
    int m = min(64, d - base);           // wave-uniform
    int ce = 0; float we = 0.f;
    if (lane < m) { ce = col[s + base + lane]; we = wgt[s + base + lane]; }
    int npairs = (m + 1) >> 1;           // wave-uniform
    f32x4 p0, p1, p2, p3; float w0, w1, w2, w3;
    LOADP(0, p0, w0); LOADP(1, p1, w1); LOADP(2, p2, w2); LOADP(3, p3, w3);
    int q = 0;
    for (; q + 4 < npairs; q += 4) {
      acc += p0 * w0; LOADP(q + 4, p0, w0);
      acc += p1 * w1; LOADP(q + 5, p1, w1);
      acc += p2 * w2; LOADP(q + 6, p2, w2);
      acc += p3 * w3; LOADP(q + 7, p3, w3);
    }
    acc += p0 * w0; acc += p1 * w1; acc += p2 * w2; acc += p3 * w3;
  }
#undef LOADP

  // combine halves (lane pairs with lane^32 hold the same features)
  acc[0] += __shfl_xor(acc[0], 32);
  acc[1] += __shfl_xor(acc[1], 32);
  acc[2] += __shfl_xor(acc[2], 32);
  acc[3] += __shfl_xor(acc[3], 32);

  if (half == 0) {
    f32x4 o;
    o[0] = fmaxf(acc[0], 0.f); o[1] = fmaxf(acc[1], 0.f);
    o[2] = fmaxf(acc[2], 0.f); o[3] = fmaxf(acc[3], 0.f);
    *(f32x4*)(hout + (size_t)node * 128 + fq) = o;
  }
}

// ---------- pooling ----------
// batch is SORTED -> boundary detection, no atomics. gstart has 65 entries.
__global__ void k_gb(const int* __restrict__ batch, int* __restrict__ gstart, int N) {
  int i = blockIdx.x * 256 + threadIdx.x;
  if (i >= N) return;
  int b = batch[i];
  int prev = (i == 0) ? -1 : batch[i - 1];
  if (b != prev) {
    for (int g = prev + 1; g <= b; ++g) gstart[g] = i;  // fills empty-graph gaps
  }
  if (i == N - 1) {
    for (int g = b + 1; g <= 64; ++g) gstart[g] = N;
  }
}

// stage 1: 4 chunks per graph, 512 threads (4 row-waves x 128 feats), no atomics
__global__ __launch_bounds__(512)
void k_pool1(const float* __restrict__ h, const int* __restrict__ gstart,
             float* __restrict__ part) {
  int g = blockIdx.x >> 2, c = blockIdx.x & 3;
  int lo = gstart[g], hi = gstart[g + 1];
  int cnt = hi - lo;
  int c0 = lo + (int)(((long long)cnt * c) >> 2);
  int c1 = lo + (int)(((long long)cnt * (c + 1)) >> 2);
  int r = threadIdx.x >> 7;      // 0..3
  int f = threadIdx.x & 127;
  float acc = 0.f;
  for (int i = c0 + r; i < c1; i += 4) acc += h[(size_t)i * 128 + f];
  __shared__ float s[4][128];
  s[r][f] = acc;
  __syncthreads();
  if (r == 0)
    part[(size_t)blockIdx.x * 128 + f] = s[0][f] + s[1][f] + s[2][f] + s[3][f];
}

// stage 2: combine 4 partials, divide by count
__global__ void k_pool2(const float* __restrict__ part, const int* __restrict__ gstart,
                        float* __restrict__ out) {
  int g = blockIdx.x, f = threadIdx.x;
  int cnt = gstart[g + 1] - gstart[g];
  float s = part[(size_t)(g * 4 + 0) * 128 + f] + part[(size_t)(g * 4 + 1) * 128 + f]
          + part[(size_t)(g * 4 + 2) * 128 + f] + part[(size_t)(g * 4 + 3) * 128 + f];
  out[g * 128 + f] = s / (float)(cnt > 0 ? cnt : 1);
}

// ---------- launcher ----------
extern "C" void kernel_launch(void* const* d_in, const int* in_sizes, int n_in,
                              void* d_out, int out_size, void* d_ws, size_t ws_size,
                              hipStream_t stream) {
  const float* x   = (const float*)d_in[0];
  const float* Wp  = (const float*)d_in[1];
  const float* bp  = (const float*)d_in[2];
  const float* Wr  = (const float*)d_in[3];
  const float* br  = (const float*)d_in[4];
  const float* Wo0 = (const float*)d_in[5];
  const float* bo0 = (const float*)d_in[6];
  const float* Wo1 = (const float*)d_in[7];
  const float* bo1 = (const float*)d_in[8];
  const int* esrc  = (const int*)d_in[9];
  const int* edst  = (const int*)d_in[10];
  const int* batch = (const int*)d_in[11];
  const int E = in_sizes[9];
  const int N = in_sizes[11];
  float* out = (float*)d_out;

  char* wsp = (char*)d_ws;
  size_t off = 0;
  auto alloc = [&](size_t bytes) {
    void* p = wsp + off;
    off += (bytes + 255) & ~(size_t)255;
    return p;
  };
  unsigned short* tb = (unsigned short*)alloc((size_t)N * 128 * 2);  // bf16 gather table
  float* h      = (float*)alloc((size_t)N * 128 * 4);
  int*   col    = (int*)alloc((size_t)E * 4);
  float* wgt    = (float*)alloc((size_t)E * 4);
  int*   start  = (int*)alloc((size_t)N * 4);
  int*   degi   = (int*)alloc((size_t)N * 4);
  int*   cursor = (int*)alloc((size_t)N * 4);   // reused as `part` after CSR build
  float* dis    = (float*)alloc((size_t)N * 4);
  unsigned short* Whi = (unsigned short*)alloc((size_t)8 * 16384 * 2);
  unsigned short* Wlo = (unsigned short*)alloc((size_t)8 * 16384 * 2);
  int*   gstart = (int*)alloc(65 * 4);
  int*   total  = (int*)alloc(16);
  float* part   = (float*)cursor;               // 256*128*4 = 128KB <= N*4 = 400KB

  hipMemsetAsync(degi,   0, (size_t)N * 4, stream);
  hipMemsetAsync(cursor, 0, (size_t)N * 4, stream);
  hipMemsetAsync(total,  0, 4, stream);

  k_deg <<<(E + 255) / 256, 256, 0, stream>>>(edst, degi, E);
  k_node<<<(N + 255) / 256, 256, 0, stream>>>(degi, start, dis, total, N);
  k_fill<<<(E + 255) / 256, 256, 0, stream>>>(esrc, edst, start, cursor, dis, col, wgt, E);
  k_wt  <<<512, 256, 0, stream>>>(Wp, Wr, Wo0, Wo1, Whi, Wlo);
  k_gb  <<<(N + 255) / 256, 256, 0, stream>>>(batch, gstart, N);

  dim3 ggrid((N + 63) / 64, 2);

  // L0: tb = x @ Wp ; h = agg(tb, bp)
  k_gemm<false, false><<<ggrid, 256, 0, stream>>>(x, Whi + 0 * 16384, Wlo + 0 * 16384, tb, N);
  k_agg<<<(N + 3) / 4, 256, 0, stream>>>(tb, col, wgt, start, degi, dis, bp, h, N);
  // L1..L4 recurrent
  for (int i = 0; i < 4; ++i) {
    k_gemm<false, false><<<ggrid, 256, 0, stream>>>(h, Whi + (1 + i) * 16384, Wlo + (1 + i) * 16384, tb, N);
    k_agg<<<(N + 3) / 4, 256, 0, stream>>>(tb, col, wgt, start, degi, dis, br + i * 128, h, N);
  }
  // L5: tb = h @ Wo0_top + relu(x) @ Wo0_bot ; h = agg(tb, bo0)
  k_gemm<false, false><<<ggrid, 256, 0, stream>>>(h, Whi + 5 * 16384, Wlo + 5 * 16384, tb, N);
  k_gemm<true,  true ><<<ggrid, 256, 0, stream>>>(x, Whi + 6 * 16384, Wlo + 6 * 16384, tb, N);
  k_agg<<<(N + 3) / 4, 256, 0, stream>>>(tb, col, wgt, start, degi, dis, bo0, h, N);
  // L6: tb = h @ Wo1 ; h = agg(tb, bo1)
  k_gemm<false, false><<<ggrid, 256, 0, stream>>>(h, Whi + 7 * 16384, Wlo + 7 * 16384, tb, N);
  k_agg<<<(N + 3) / 4, 256, 0, stream>>>(tb, col, wgt, start, degi, dis, bo1, h, N);

  // mean pool (2-stage, deterministic)
  k_pool1<<<256, 512, 0, stream>>>(h, gstart, part);
  k_pool2<<<64, 128, 0, stream>>>(part, gstart, out);
}

// Round 15
// 988.446 us; speedup vs baseline: 2.3365x; 1.0073x over previous
//
#include <hip/hip_runtime.h>

typedef __attribute__((ext_vector_type(8))) short short8;
typedef __attribute__((ext_vector_type(4))) float f32x4;
typedef __attribute__((ext_vector_type(4))) unsigned short us4;

// ---------- helpers ----------
__device__ __forceinline__ unsigned short f2bf(float f) {
  unsigned int u = __float_as_uint(f);
  u = u + 0x7fffu + ((u >> 16) & 1u);   // RNE
  return (unsigned short)(u >> 16);
}
__device__ __forceinline__ float bf2f(unsigned short h) {
  return __uint_as_float(((unsigned int)h) << 16);
}
// element (r,k) of a [R][128] bf16 tile -> swizzled byte offset
__device__ __forceinline__ int swz(int r, int k) {
  return (((r * 128 + k) * 2) ^ ((r & 7) << 4));
}

// ---------- CSR build ----------
__global__ void k_deg(const int* __restrict__ edst, int* __restrict__ degi, int E) {
  int e = blockIdx.x * 256 + threadIdx.x;
  if (e < E) atomicAdd(&degi[edst[e]], 1);
}

__global__ void k_node(const int* __restrict__ degi, int* __restrict__ start,
                       float* __restrict__ dis, int* __restrict__ total, int N) {
  int tid = threadIdx.x;
  int i = blockIdx.x * 256 + tid;
  int d = (i < N) ? degi[i] : 0;
  __shared__ int sd[256];
  sd[tid] = d; __syncthreads();
  #pragma unroll
  for (int off = 1; off < 256; off <<= 1) {
    int v = (tid >= off) ? sd[tid - off] : 0;
    __syncthreads();
    sd[tid] += v;
    __syncthreads();
  }
  __shared__ int sbase;
  if (tid == 255) sbase = atomicAdd(total, sd[255]);
  __syncthreads();
  if (i < N) {
    start[i] = sbase + sd[tid] - d;   // exclusive prefix within global alloc
    dis[i] = rsqrtf(1.0f + (float)d);
  }
}

// fill: col only (4B/edge scatter). Edge weight dis[s]*dis[d] is recomputed
// in k_agg from L2-resident dis[] -> halves the scattered-write footprint.
__global__ void k_fill(const int* __restrict__ esrc, const int* __restrict__ edst,
                       const int* __restrict__ start, int* __restrict__ cursor,
                       int* __restrict__ col, int E) {
  int e = blockIdx.x * 256 + threadIdx.x;
  if (e >= E) return;
  int d = edst[e], s = esrc[e];
  int p = start[d] + atomicAdd(&cursor[d], 1);
  col[p] = s;
}

// ---------- weight prep: bf16 hi/lo split of W^T, computed ONCE ----------
__global__ void k_wt(const float* __restrict__ Wp, const float* __restrict__ Wr,
                     const float* __restrict__ Wo0, const float* __restrict__ Wo1,
                     unsigned short* __restrict__ Whi, unsigned short* __restrict__ Wlo) {
  int idx = blockIdx.x * 256 + threadIdx.x;
  if (idx >= 8 * 16384) return;
  int m = idx >> 14, rem = idx & 16383;
  int c = rem >> 7, k = rem & 127;
  float v;
  if (m == 0)       v = Wp[k * 128 + c];
  else if (m <= 4)  v = Wr[(m - 1) * 16384 + k * 128 + c];
  else if (m == 5)  v = Wo0[k * 128 + c];
  else if (m == 6)  v = Wo0[(128 + k) * 128 + c];
  else              v = Wo1[k * 128 + c];
  unsigned short hh = f2bf(v);
  Whi[idx] = hh;
  Wlo[idx] = f2bf(v - bf2f(hh));
}

// ---------- GEMM: TB[N,128](bf16) (+)= A[N,128] @ W ----------
// ABF16=false: A is fp32 -> bf16x3 split (Ahi*Whi + Ahi*Wlo + Alo*Whi).
// ABF16=true:  A is bf16 (exact)  -> 2 MFMAs (A*Whi + A*Wlo), no A-split,
//              48KB LDS (no ALO region), straight-copy A staging.
template<bool ACC, bool RELU_A, bool ABF16>
__global__ __launch_bounds__(256)
void k_gemm(const void* __restrict__ Av, const unsigned short* __restrict__ Whi,
            const unsigned short* __restrict__ Wlo, unsigned short* __restrict__ TB, int N) {
  constexpr int AHI_OFF = 0;
  constexpr int WHI_OFF = 16384;
  constexpr int WLO_OFF = 32768;
  constexpr int ALO_OFF = 49152;              // fp32 path only
  __shared__ __align__(16) char smem[ABF16 ? 49152 : 65536];
  const int tid = threadIdx.x;
  const int grow = blockIdx.x * 64;
  const int cb = blockIdx.y * 64;

  #pragma unroll
  for (int it = 0; it < 4; ++it) {
    int id = it * 256 + tid;
    int r = id >> 4;            // 0..63
    int kp = (id & 15) * 8;     // 0..120
    int ga = grow + r; if (ga > N - 1) ga = N - 1;
    if constexpr (ABF16) {
      const unsigned short* ap = (const unsigned short*)Av + (size_t)ga * 128 + kp;
      *(short8*)(smem + AHI_OFF + swz(r, kp)) = *(const short8*)ap;
    } else {
      const float* ap = (const float*)Av + (size_t)ga * 128 + kp;
      float4 a0 = *(const float4*)ap;
      float4 a1 = *(const float4*)(ap + 4);
      if (RELU_A) {
        a0.x = fmaxf(a0.x, 0.f); a0.y = fmaxf(a0.y, 0.f); a0.z = fmaxf(a0.z, 0.f); a0.w = fmaxf(a0.w, 0.f);
        a1.x = fmaxf(a1.x, 0.f); a1.y = fmaxf(a1.y, 0.f); a1.z = fmaxf(a1.z, 0.f); a1.w = fmaxf(a1.w, 0.f);
      }
      float fv[8] = {a0.x, a0.y, a0.z, a0.w, a1.x, a1.y, a1.z, a1.w};
      short8 hi, lo;
      #pragma unroll
      for (int q = 0; q < 8; ++q) {
        unsigned short hh = f2bf(fv[q]);
        hi[q] = (short)hh;
        lo[q] = (short)f2bf(fv[q] - bf2f(hh));
      }
      *(short8*)(smem + AHI_OFF + swz(r, kp)) = hi;
      *(short8*)(smem + ALO_OFF + swz(r, kp)) = lo;
    }
    // W tile: pre-split bf16, straight copy global -> LDS
    size_t wo = (size_t)(cb + r) * 128 + kp;
    *(short8*)(smem + WHI_OFF + swz(r, kp)) = *(const short8*)(Whi + wo);
    *(short8*)(smem + WLO_OFF + swz(r, kp)) = *(const short8*)(Wlo + wo);
  }
  __syncthreads();

  const int l = tid & 63;
  const int w = tid >> 6;           // 0..3
  const int wr = (w >> 1) * 32;     // 0 or 32
  const int wc = (w & 1) * 32;      // 0 or 32
  const int lr = l & 15;
  const int lk = (l >> 4) * 8;

  f32x4 acc[2][2];
  #pragma unroll
  for (int i = 0; i < 2; ++i)
    #pragma unroll
    for (int j = 0; j < 2; ++j)
      acc[i][j] = (f32x4){0.f, 0.f, 0.f, 0.f};

  #pragma unroll
  for (int kk = 0; kk < 4; ++kk) {
    int k0 = kk * 32 + lk;
    short8 ahi[2], alo[2], bhi[2], blo[2];
    #pragma unroll
    for (int i = 0; i < 2; ++i) {
      int r = wr + i * 16 + lr;
      ahi[i] = *(const short8*)(smem + AHI_OFF + swz(r, k0));
      if constexpr (!ABF16)
        alo[i] = *(const short8*)(smem + ALO_OFF + swz(r, k0));
    }
    #pragma unroll
    for (int j = 0; j < 2; ++j) {
      int c = wc + j * 16 + lr;
      bhi[j] = *(const short8*)(smem + WHI_OFF + swz(c, k0));
      blo[j] = *(const short8*)(smem + WLO_OFF + swz(c, k0));
    }
    #pragma unroll
    for (int i = 0; i < 2; ++i)
      #pragma unroll
      for (int j = 0; j < 2; ++j) {
        acc[i][j] = __builtin_amdgcn_mfma_f32_16x16x32_bf16(ahi[i], bhi[j], acc[i][j], 0, 0, 0);
        acc[i][j] = __builtin_amdgcn_mfma_f32_16x16x32_bf16(ahi[i], blo[j], acc[i][j], 0, 0, 0);
        if constexpr (!ABF16)
          acc[i][j] = __builtin_amdgcn_mfma_f32_16x16x32_bf16(alo[i], bhi[j], acc[i][j], 0, 0, 0);
      }
  }

  #pragma unroll
  for (int i = 0; i < 2; ++i)
    #pragma unroll
    for (int j = 0; j < 2; ++j)
      #pragma unroll
      for (int r = 0; r < 4; ++r) {
        int row = grow + wr + i * 16 + (l >> 4) * 4 + r;
        int c = cb + wc + j * 16 + lr;
        if (row < N) {
          size_t idx = (size_t)row * 128 + c;
          float v = acc[i][j][r];
          if (ACC) v += bf2f(TB[idx]);
          TB[idx] = f2bf(v);
        }
      }
}

// ---------- aggregation: hb[i] = relu( sum_in tb[src]*dis[src]*dis[i] + tb[i]*dis[i]^2 + b ) ----------
// One wave per node. Pair-gather over bf16 rows (256B); edge weight from
// L2-resident dis[]. UNIFORM control flow (proven R9). Output bf16.
__global__ __launch_bounds__(256)
void k_agg(const unsigned short* __restrict__ tb, const int* __restrict__ col,
           const int* __restrict__ start, const int* __restrict__ degi,
           const float* __restrict__ dis, const float* __restrict__ bias,
           unsigned short* __restrict__ hb, int N) {
  int node = blockIdx.x * 4 + (threadIdx.x >> 6);
  if (node >= N) return;
  int lane = threadIdx.x & 63;
  int half = lane >> 5;          // 0 or 1
  int fq = (lane & 31) * 4;      // feature offset (4 features per lane)

  float dsv = dis[node];
  float sn = dsv * dsv;
  f32x4 acc = (f32x4){0.f, 0.f, 0.f, 0.f};
  if (half == 0) {
    us4 sv = *(const us4*)(tb + (size_t)node * 128 + fq);
    float4 bv = *(const float4*)(bias + fq);
    acc[0] = bf2f(sv[0]) * sn + bv.x;
    acc[1] = bf2f(sv[1]) * sn + bv.y;
    acc[2] = bf2f(sv[2]) * sn + bv.z;
    acc[3] = bf2f(sv[3]) * sn + bv.w;
  }

#define LOADP(k, rr, ww) { int ii = 2 * (k) + half;                       \
    int ss = __shfl(ce, ii & 63); float wv = __shfl(we, ii & 63);         \
    ww = (ii < m) ? wv : 0.f;                                             \
    us4 u = *(const us4*)(tb + (size_t)ss * 128 + fq);                    \
    rr[0] = bf2f(u[0]); rr[1] = bf2f(u[1]);                               \
    rr[2] = bf2f(u[2]); rr[3] = bf2f(u[3]); }

  int s = start[node], d = degi[node];
  for (int base = 0; base < d; base += 64) {
    int m = min(64, d - base);           // wave-uniform
    int ce = 0; float we = 0.f;
    if (lane < m) {
      ce = col[s + base + lane];
      we = dis[ce] * dsv;                // edge weight: L2-resident gather
    }
    int npairs = (m + 1) >> 1;           // wave-uniform
    f32x4 p0, p1, p2, p3; float w0, w1, w2, w3;
    LOADP(0, p0, w0); LOADP(1, p1, w1); LOADP(2, p2, w2); LOADP(3, p3, w3);
    int q = 0;
    for (; q + 4 < npairs; q += 4) {
      acc += p0 * w0; LOADP(q + 4, p0, w0);
      acc += p1 * w1; LOADP(q + 5, p1, w1);
      acc += p2 * w2; LOADP(q + 6, p2, w2);
      acc += p3 * w3; LOADP(q + 7, p3, w3);
    }
    acc += p0 * w0; acc += p1 * w1; acc += p2 * w2; acc += p3 * w3;
  }
#undef LOADP

  // combine halves (lane pairs with lane^32 hold the same features)
  acc[0] += __shfl_xor(acc[0], 32);
  acc[1] += __shfl_xor(acc[1], 32);
  acc[2] += __shfl_xor(acc[2], 32);
  acc[3] += __shfl_xor(acc[3], 32);

  if (half == 0) {
    us4 o;
    o[0] = f2bf(fmaxf(acc[0], 0.f)); o[1] = f2bf(fmaxf(acc[1], 0.f));
    o[2] = f2bf(fmaxf(acc[2], 0.f)); o[3] = f2bf(fmaxf(acc[3], 0.f));
    *(us4*)(hb + (size_t)node * 128 + fq) = o;
  }
}

// ---------- pooling ----------
// batch is SORTED -> boundary detection, no atomics. gstart has 65 entries.
__global__ void k_gb(const int* __restrict__ batch, int* __restrict__ gstart, int N) {
  int i = blockIdx.x * 256 + threadIdx.x;
  if (i >= N) return;
  int b = batch[i];
  int prev = (i == 0) ? -1 : batch[i - 1];
  if (b != prev) {
    for (int g = prev + 1; g <= b; ++g) gstart[g] = i;  // fills empty-graph gaps
  }
  if (i == N - 1) {
    for (int g = b + 1; g <= 64; ++g) gstart[g] = N;
  }
}

// stage 1: 4 chunks per graph, 512 threads (4 row-waves x 128 feats), no atomics
__global__ __launch_bounds__(512)
void k_pool1(const unsigned short* __restrict__ hb, const int* __restrict__ gstart,
             float* __restrict__ part) {
  int g = blockIdx.x >> 2, c = blockIdx.x & 3;
  int lo = gstart[g], hi = gstart[g + 1];
  int cnt = hi - lo;
  int c0 = lo + (int)(((long long)cnt * c) >> 2);
  int c1 = lo + (int)(((long long)cnt * (c + 1)) >> 2);
  int r = threadIdx.x >> 7;      // 0..3
  int f = threadIdx.x & 127;
  float acc = 0.f;
  for (int i = c0 + r; i < c1; i += 4) acc += bf2f(hb[(size_t)i * 128 + f]);
  __shared__ float s[4][128];
  s[r][f] = acc;
  __syncthreads();
  if (r == 0)
    part[(size_t)blockIdx.x * 128 + f] = s[0][f] + s[1][f] + s[2][f] + s[3][f];
}

// stage 2: combine 4 partials, divide by count
__global__ void k_pool2(const float* __restrict__ part, const int* __restrict__ gstart,
                        float* __restrict__ out) {
  int g = blockIdx.x, f = threadIdx.x;
  int cnt = gstart[g + 1] - gstart[g];
  float s = part[(size_t)(g * 4 + 0) * 128 + f] + part[(size_t)(g * 4 + 1) * 128 + f]
          + part[(size_t)(g * 4 + 2) * 128 + f] + part[(size_t)(g * 4 + 3) * 128 + f];
  out[g * 128 + f] = s / (float)(cnt > 0 ? cnt : 1);
}

// ---------- launcher ----------
extern "C" void kernel_launch(void* const* d_in, const int* in_sizes, int n_in,
                              void* d_out, int out_size, void* d_ws, size_t ws_size,
                              hipStream_t stream) {
  const float* x   = (const float*)d_in[0];
  const float* Wp  = (const float*)d_in[1];
  const float* bp  = (const float*)d_in[2];
  const float* Wr  = (const float*)d_in[3];
  const float* br  = (const float*)d_in[4];
  const float* Wo0 = (const float*)d_in[5];
  const float* bo0 = (const float*)d_in[6];
  const float* Wo1 = (const float*)d_in[7];
  const float* bo1 = (const float*)d_in[8];
  const int* esrc  = (const int*)d_in[9];
  const int* edst  = (const int*)d_in[10];
  const int* batch = (const int*)d_in[11];
  const int E = in_sizes[9];
  const int N = in_sizes[11];
  float* out = (float*)d_out;

  char* wsp = (char*)d_ws;
  size_t off = 0;
  auto alloc = [&](size_t bytes) {
    void* p = wsp + off;
    off += (bytes + 255) & ~(size_t)255;
    return p;
  };
  unsigned short* tb = (unsigned short*)alloc((size_t)N * 128 * 2);  // bf16 gather table
  unsigned short* hb = (unsigned short*)alloc((size_t)N * 128 * 2);  // bf16 h buffer
  int*   col    = (int*)alloc((size_t)E * 4);
  int*   start  = (int*)alloc((size_t)N * 4);
  int*   degi   = (int*)alloc((size_t)N * 4);
  int*   cursor = (int*)alloc((size_t)N * 4);   // reused as `part` after CSR build
  float* dis    = (float*)alloc((size_t)N * 4);
  unsigned short* Whi = (unsigned short*)alloc((size_t)8 * 16384 * 2);
  unsigned short* Wlo = (unsigned short*)alloc((size_t)8 * 16384 * 2);
  int*   gstart = (int*)alloc(65 * 4);
  int*   total  = (int*)alloc(16);
  float* part   = (float*)cursor;               // 256*128*4 = 128KB <= N*4 = 400KB

  hipMemsetAsync(degi,   0, (size_t)N * 4, stream);
  hipMemsetAsync(cursor, 0, (size_t)N * 4, stream);
  hipMemsetAsync(total,  0, 4, stream);

  k_deg <<<(E + 255) / 256, 256, 0, stream>>>(edst, degi, E);
  k_node<<<(N + 255) / 256, 256, 0, stream>>>(degi, start, dis, total, N);
  k_fill<<<(E + 255) / 256, 256, 0, stream>>>(esrc, edst, start, cursor, col, E);
  k_wt  <<<512, 256, 0, stream>>>(Wp, Wr, Wo0, Wo1, Whi, Wlo);
  k_gb  <<<(N + 255) / 256, 256, 0, stream>>>(batch, gstart, N);

  dim3 ggrid((N + 63) / 64, 2);

  // L0: tb = x @ Wp ; hb = agg(tb, bp)
  k_gemm<false, false, false><<<ggrid, 256, 0, stream>>>(x, Whi + 0 * 16384, Wlo + 0 * 16384, tb, N);
  k_agg<<<(N + 3) / 4, 256, 0, stream>>>(tb, col, start, degi, dis, bp, hb, N);
  // L1..L4 recurrent (bf16 A path: 2 MFMAs, straight-copy staging)
  for (int i = 0; i < 4; ++i) {
    k_gemm<false, false, true><<<ggrid, 256, 0, stream>>>(hb, Whi + (1 + i) * 16384, Wlo + (1 + i) * 16384, tb, N);
    k_agg<<<(N + 3) / 4, 256, 0, stream>>>(tb, col, start, degi, dis, br + i * 128, hb, N);
  }
  // L5: tb = hb @ Wo0_top + relu(x) @ Wo0_bot ; hb = agg(tb, bo0)
  k_gemm<false, false, true ><<<ggrid, 256, 0, stream>>>(hb, Whi + 5 * 16384, Wlo + 5 * 16384, tb, N);
  k_gemm<true,  true,  false><<<ggrid, 256, 0, stream>>>(x, Whi + 6 * 16384, Wlo + 6 * 16384, tb, N);
  k_agg<<<(N + 3) / 4, 256, 0, stream>>>(tb, col, start, degi, dis, bo0, hb, N);
  // L6: tb = hb @ Wo1 ; hb = agg(tb, bo1)
  k_gemm<false, false, true><<<ggrid, 256, 0, stream>>>(hb, Whi + 7 * 16384, Wlo + 7 * 16384, tb, N);
  k_agg<<<(N + 3) / 4, 256, 0, stream>>>(tb, col, start, degi, dis, bo1, hb, N);

  // mean pool (2-stage, deterministic)
  k_pool1<<<256, 512, 0, stream>>>(hb, gstart, part);
  k_pool2<<<64, 128, 0, stream>>>(part, gstart, out);
}